// Round 23
// baseline (1085.943 us; speedup 1.0000x reference)
//
#include <hip/hip_runtime.h>

typedef _Float16 f16;
typedef _Float16 f16x8 __attribute__((ext_vector_type(8)));
typedef float f32x4 __attribute__((ext_vector_type(4)));

__device__ __forceinline__ f32x4 mfma16(f16x8 a, f16x8 b, f32x4 c) {
    return __builtin_amdgcn_mfma_f32_16x16x32_f16(a, b, c, 0, 0, 0);
}

// ---------------- main implicit-GEMM 3x3 conv, f16 MFMA (r10-proven core) ----------------
// Epilogue SELF-ZEROES the output halo (edge blocks only, own oc-slice).
template<int IC, int OC, int BX, int WY, int WO, int MT, int NT, bool POOL>
__global__ __launch_bounds__(256) void convmf_k(
    const f16* __restrict__ in, const f16* __restrict__ wt,
    const float* __restrict__ bias, f16* __restrict__ out,
    int H, int W, int ocBlocks, long inStride, long outStride)
{
    constexpr int WROWS = MT * 16 / BX;
    constexpr int BROWS = WROWS * WY;
    constexpr int SR = BROWS + 2;
    constexpr int SC = BX + 2;
    constexpr int LOG = (BX == 64) ? 6 : 5;
    constexpr int OCB = 16 * NT * WO;     // channels covered per block
    static_assert(!POOL || (BX == 64 && MT == 8), "pool path assumes BX==64, MT==8");
    __shared__ f16 lds[SR * SC * 40];

    const int tid  = threadIdx.x;
    const int lane = tid & 63;
    const int wv   = tid >> 6;
    const int wy   = wv / WO;
    const int wo   = wv % WO;
    const int lm   = lane & 15;
    const int lk   = lane >> 4;
    const int x0   = blockIdx.x * BX;
    const int y0   = blockIdx.y * BROWS;
    const int zb   = blockIdx.z;
    const int n    = zb / ocBlocks;
    const int ocbase = (zb - n * ocBlocks) * OCB;
    const int oc0  = ocbase + wo * (16 * NT);
    in  += (long)n * inStride;
    out += (long)n * outStride;

    f32x4 acc[MT][NT];
#pragma unroll
    for (int mt = 0; mt < MT; ++mt)
#pragma unroll
        for (int nt = 0; nt < NT; ++nt)
            acc[mt][nt] = (f32x4){0.f, 0.f, 0.f, 0.f};

    const int Wp = W + 2;
    for (int ic0 = 0; ic0 < IC; ic0 += 32) {
        if (ic0) __syncthreads();
        const f16* ip = in + ((long)y0 * Wp + x0) * IC + ic0;
        constexpr int TASKS = SR * SC * 4;
        for (int s = tid; s < TASKS; s += 256) {
            int r    = s / (SC * 4);
            int rem  = s - r * (SC * 4);
            int xcol = rem >> 2;
            int g    = rem & 3;
            f16x8 v = *(const f16x8*)(ip + ((long)r * Wp + xcol) * IC + g * 8);
            *(f16x8*)&lds[(r * SC + xcol) * 40 + g * 8] = v;
        }
        __syncthreads();

        for (int t = 0; t < 9; ++t) {
            int dy = t / 3, dx = t - dy * 3;
            const f16* wp = wt + ((long)t * OC + oc0) * IC + ic0 + lk * 8;
            f16x8 bfr[NT];
#pragma unroll
            for (int nt = 0; nt < NT; ++nt)
                bfr[nt] = *(const f16x8*)(wp + (nt * 16 + lm) * IC);
#pragma unroll
            for (int mt = 0; mt < MT; ++mt) {
                int pos = mt * 16 + lm;
                int xx = pos & (BX - 1);
                int yy = wy * WROWS + (pos >> LOG);
                f16x8 a = *(const f16x8*)&lds[((yy + dy) * SC + xx + dx) * 40 + lk * 8];
#pragma unroll
                for (int nt = 0; nt < NT; ++nt)
                    acc[mt][nt] = mfma16(a, bfr[nt], acc[mt][nt]);
            }
        }
    }

    f16x8 z8;
#pragma unroll
    for (int j = 0; j < 8; ++j) z8[j] = (f16)0.f;

    if constexpr (!POOL) {
#pragma unroll
        for (int nt = 0; nt < NT; ++nt) {
            int oc = oc0 + nt * 16 + lm;
            float bs = bias[oc];
#pragma unroll
            for (int mt = 0; mt < MT; ++mt) {
#pragma unroll
                for (int r = 0; r < 4; ++r) {
                    int pos = mt * 16 + lk * 4 + r;
                    int xx = pos & (BX - 1);
                    int yy = wy * WROWS + (pos >> LOG);
                    float v = fmaxf(acc[mt][nt][r] + bs, 0.f);
                    out[((long)(y0 + yy + 1) * (W + 2) + (x0 + xx + 1)) * OC + oc] = (f16)v;
                }
            }
        }
        if (y0 == 0 || y0 + BROWS == H) {
            int c0 = (x0 == 0) ? 0 : x0 + 1;
            int c1 = (x0 + BX == W) ? (W + 1) : (x0 + BX);
            int ncol = c1 - c0 + 1;
            int total = ncol * (OCB / 8);
            for (int pass = 0; pass < 2; ++pass) {
                int row = (pass == 0) ? 0 : H + 1;
                if ((pass == 0 && y0 == 0) || (pass == 1 && y0 + BROWS == H)) {
                    for (int s = tid; s < total; s += 256) {
                        int col = c0 + s / (OCB / 8);
                        int gg = s - (col - c0) * (OCB / 8);
                        *(f16x8*)&out[((long)row * (W + 2) + col) * OC + ocbase + gg * 8] = z8;
                    }
                }
            }
        }
        if (x0 == 0 || x0 + BX == W) {
            int total = BROWS * (OCB / 8);
            for (int pass = 0; pass < 2; ++pass) {
                int col = (pass == 0) ? 0 : W + 1;
                if ((pass == 0 && x0 == 0) || (pass == 1 && x0 + BX == W)) {
                    for (int s = tid; s < total; s += 256) {
                        int row = y0 + 1 + s / (OCB / 8);
                        int gg = s - (row - y0 - 1) * (OCB / 8);
                        *(f16x8*)&out[((long)row * (W + 2) + col) * OC + ocbase + gg * 8] = z8;
                    }
                }
            }
        }
    } else {
        const int Wo = W >> 1;
        const int Ho = H >> 1;
#pragma unroll
        for (int nt = 0; nt < NT; ++nt) {
            int oc = oc0 + nt * 16 + lm;
            float bs = bias[oc];
#pragma unroll
            for (int mt = 0; mt < 4; ++mt) {
#pragma unroll
                for (int r = 0; r < 4; r += 2) {
                    float v = fmaxf(fmaxf(acc[mt][nt][r], acc[mt][nt][r + 1]),
                                    fmaxf(acc[mt + 4][nt][r], acc[mt + 4][nt][r + 1]));
                    v = fmaxf(v + bs, 0.f);
                    int pos = mt * 16 + lk * 4 + r;
                    int xo = pos >> 1;
                    out[((long)((y0 >> 1) + wy + 1) * (Wo + 2) + ((x0 >> 1) + xo + 1)) * OC + oc] = (f16)v;
                }
            }
        }
        const int px0 = x0 >> 1;
        const int py0 = y0 >> 1;
        if (y0 == 0 || y0 + BROWS == H) {
            int c0 = (x0 == 0) ? 0 : px0 + 1;
            int c1 = (x0 + BX == W) ? (Wo + 1) : (px0 + BX / 2);
            int ncol = c1 - c0 + 1;
            int total = ncol * (OCB / 8);
            for (int pass = 0; pass < 2; ++pass) {
                int row = (pass == 0) ? 0 : Ho + 1;
                if ((pass == 0 && y0 == 0) || (pass == 1 && y0 + BROWS == H)) {
                    for (int s = tid; s < total; s += 256) {
                        int col = c0 + s / (OCB / 8);
                        int gg = s - (col - c0) * (OCB / 8);
                        *(f16x8*)&out[((long)row * (Wo + 2) + col) * OC + ocbase + gg * 8] = z8;
                    }
                }
            }
        }
        if (x0 == 0 || x0 + BX == W) {
            constexpr int PROWS = BROWS / 2;
            int total = PROWS * (OCB / 8);
            for (int pass = 0; pass < 2; ++pass) {
                int col = (pass == 0) ? 0 : Wo + 1;
                if ((pass == 0 && x0 == 0) || (pass == 1 && x0 + BX == W)) {
                    for (int s = tid; s < total; s += 256) {
                        int row = py0 + 1 + s / (OCB / 8);
                        int gg = s - (row - py0 - 1) * (OCB / 8);
                        *(f16x8*)&out[((long)row * (Wo + 2) + col) * OC + ocbase + gg * 8] = z8;
                    }
                }
            }
        }
    }
}

// ---------------- conv1: IC=2, im2col in LDS, K padded to 32 (r5-proven) ----------------
__global__ __launch_bounds__(256) void convmf1_k(
    const float* __restrict__ x, int itemBase,
    const f16* __restrict__ wt1,  // [64][32] f16, k=2t+ic, zero-padded
    const float* __restrict__ bias, f16* __restrict__ out, long outStride)
{
    __shared__ f16 ldsx[10 * 66 * 2];
    __shared__ f16 ldsa[512 * 40];
    const int tid = threadIdx.x;
    const int lane = tid & 63;
    const int wv = tid >> 6;
    const int lm = lane & 15;
    const int lk = lane >> 4;
    const int x0 = blockIdx.x * 64;
    const int y0 = blockIdx.y * 8;
    const float* xb = x + (long)(itemBase + blockIdx.z) * 2 * 512 * 512;
    out += (long)blockIdx.z * outStride;

    for (int s = tid; s < 660; s += 256) {
        int r = s / 66, xc = s - r * 66;
        int gy = y0 + r - 1, gx = x0 + xc - 1;
        f16 v0 = (f16)0.f, v1 = (f16)0.f;
        if ((unsigned)gy < 512u && (unsigned)gx < 512u) {
            v0 = (f16)xb[(long)gy * 512 + gx];
            v1 = (f16)xb[262144 + (long)gy * 512 + gx];
        }
        ldsx[(r * 66 + xc) * 2]     = v0;
        ldsx[(r * 66 + xc) * 2 + 1] = v1;
    }
    __syncthreads();
    for (int s = tid; s < 2048; s += 256) {
        int pos = s >> 2, g = s & 3;
        int row = pos >> 6, col = pos & 63;
        f16x8 v;
#pragma unroll
        for (int j = 0; j < 8; ++j) {
            int k = g * 8 + j;
            f16 val = (f16)0.f;
            if (k < 18) {
                int t = k >> 1, ic = k & 1;
                int dy = t / 3, dx = t - dy * 3;
                val = ldsx[((row + dy) * 66 + col + dx) * 2 + ic];
            }
            v[j] = val;
        }
        *(f16x8*)&ldsa[pos * 40 + g * 8] = v;
    }
    __syncthreads();

    f32x4 acc[8][4];
#pragma unroll
    for (int mt = 0; mt < 8; ++mt)
#pragma unroll
        for (int nt = 0; nt < 4; ++nt)
            acc[mt][nt] = (f32x4){0.f, 0.f, 0.f, 0.f};

    f16x8 b0 = *(const f16x8*)(wt1 + (0 * 16 + lm) * 32 + lk * 8);
    f16x8 b1 = *(const f16x8*)(wt1 + (1 * 16 + lm) * 32 + lk * 8);
    f16x8 b2 = *(const f16x8*)(wt1 + (2 * 16 + lm) * 32 + lk * 8);
    f16x8 b3 = *(const f16x8*)(wt1 + (3 * 16 + lm) * 32 + lk * 8);
#pragma unroll
    for (int mt = 0; mt < 8; ++mt) {
        int pos = wv * 128 + mt * 16 + lm;
        f16x8 a = *(const f16x8*)&ldsa[pos * 40 + lk * 8];
        acc[mt][0] = mfma16(a, b0, acc[mt][0]);
        acc[mt][1] = mfma16(a, b1, acc[mt][1]);
        acc[mt][2] = mfma16(a, b2, acc[mt][2]);
        acc[mt][3] = mfma16(a, b3, acc[mt][3]);
    }
#pragma unroll
    for (int nt = 0; nt < 4; ++nt) {
        int oc = nt * 16 + lm;
        float bs = bias[oc];
#pragma unroll
        for (int mt = 0; mt < 8; ++mt) {
#pragma unroll
            for (int r = 0; r < 4; ++r) {
                int pos = wv * 128 + mt * 16 + lk * 4 + r;
                int xx = pos & 63, yy = pos >> 6;
                float v = fmaxf(acc[mt][nt][r] + bs, 0.f);
                out[((long)(y0 + yy + 1) * 514 + (x0 + xx + 1)) * 64 + oc] = (f16)v;
            }
        }
    }

    f16x8 z8;
#pragma unroll
    for (int j = 0; j < 8; ++j) z8[j] = (f16)0.f;
    if (y0 == 0 || y0 + 8 == 512) {
        int c0 = (x0 == 0) ? 0 : x0 + 1;
        int c1 = (x0 + 64 == 512) ? 513 : (x0 + 64);
        int ncol = c1 - c0 + 1;
        int total = ncol * 8;
        for (int pass = 0; pass < 2; ++pass) {
            int row = (pass == 0) ? 0 : 513;
            if ((pass == 0 && y0 == 0) || (pass == 1 && y0 + 8 == 512)) {
                for (int s = tid; s < total; s += 256) {
                    int col = c0 + (s >> 3);
                    int gg = s & 7;
                    *(f16x8*)&out[((long)row * 514 + col) * 64 + gg * 8] = z8;
                }
            }
        }
    }
    if (x0 == 0 || x0 + 64 == 512) {
        int total = 8 * 8;
        for (int pass = 0; pass < 2; ++pass) {
            int col = (pass == 0) ? 0 : 513;
            if ((pass == 0 && x0 == 0) || (pass == 1 && x0 + 64 == 512)) {
                for (int s = tid; s < total; s += 256) {
                    int row = y0 + 1 + (s >> 3);
                    int gg = s & 7;
                    *(f16x8*)&out[((long)row * 514 + col) * 64 + gg * 8] = z8;
                }
            }
        }
    }
}

// ---------------- merged heads: both scales in ONE dispatch ----------------
__global__ __launch_bounds__(256) void headall_k(
    const f16* __restrict__ s1v, const f16* __restrict__ s2v,
    const f16* __restrict__ wth1, const f16* __restrict__ wth2,
    const float* __restrict__ lb1, const float* __restrict__ cb1, const float* __restrict__ rb1,
    const float* __restrict__ lb2, const float* __restrict__ cb2, const float* __restrict__ rb2,
    float* __restrict__ loc, float* __restrict__ conf, float* __restrict__ regr)
{
    __shared__ f16 lds[3 * 66 * 40];   // max(3*66, 4*34) * 40
    const int tid = threadIdx.x;
    const int lane = tid & 63;
    const int wv = tid >> 6;
    const int lm = lane & 15;
    const int lk = lane >> 4;
    const int b = blockIdx.z;

    const bool big = (blockIdx.y < 64);
    const int W   = big ? 64 : 32;
    const int LOG = big ? 6 : 5;
    const int BY  = big ? 1 : 2;
    const int y0  = big ? (int)blockIdx.y : ((int)blockIdx.y - 64) * 2;
    const int posoff = big ? 0 : 4096;
    const f16* s   = big ? (s1v + (long)b * 1115136) : (s2v + (long)b * 295936);
    const f16* wth = big ? wth1 : wth2;
    const float* lb = big ? lb1 : lb2;
    const float* cb = big ? cb1 : cb2;
    const float* rb = big ? rb1 : rb2;

    const int SR = BY + 2, SC = W + 2;
    const int Wp = W + 2;

    f32x4 acc = (f32x4){0.f, 0.f, 0.f, 0.f};
    for (int ic0 = 0; ic0 < 256; ic0 += 32) {
        if (ic0) __syncthreads();
        const f16* ip = s + (long)y0 * Wp * 256 + ic0;
        const int TASKS = SR * SC * 4;
        for (int t = tid; t < TASKS; t += 256) {
            int r = t / (SC * 4);
            int rem = t - r * (SC * 4);
            int xcol = rem >> 2, g = rem & 3;
            f16x8 v = *(const f16x8*)(ip + ((long)r * Wp + xcol) * 256 + g * 8);
            *(f16x8*)&lds[(r * SC + xcol) * 40 + g * 8] = v;
        }
        __syncthreads();
        for (int t = 0; t < 9; ++t) {
            int dy = t / 3, dx = t - dy * 3;
            f16x8 bf = *(const f16x8*)(wth + ((long)t * 16 + lm) * 256 + ic0 + lk * 8);
            int pos = wv * 16 + lm;
            int xx = pos & (W - 1), yy = pos >> LOG;
            f16x8 a = *(const f16x8*)&lds[((yy + dy) * SC + xx + dx) * 40 + lk * 8];
            acc = mfma16(a, bf, acc);
        }
    }
#pragma unroll
    for (int r = 0; r < 4; ++r) {
        int pos = wv * 16 + lk * 4 + r;
        int xx = pos & (W - 1), yy = pos >> LOG;
        int P = posoff + (y0 + yy) * W + xx;
        float v = acc[r];
        if (lm < 2)       loc[((long)b * 5120 + P) * 2 + lm]       = v + lb[lm];
        else if (lm < 5)  conf[((long)b * 5120 + P) * 3 + (lm - 2)] = v + cb[lm - 2];
        else if (lm == 5) regr[(long)b * 5120 + P]                  = v + rb[0];
    }
}

// ---------------- merged weight conversions + priors (one dispatch) ----------------
__global__ __launch_bounds__(256) void cvt_all_k(
    const float* __restrict__ w1, const float* __restrict__ w2, const float* __restrict__ w3,
    const float* __restrict__ w4, const float* __restrict__ w5, const float* __restrict__ w6,
    const float* __restrict__ w7, const float* __restrict__ w8,
    const float* __restrict__ lw1, const float* __restrict__ cw1, const float* __restrict__ rw1,
    const float* __restrict__ lw2, const float* __restrict__ cw2, const float* __restrict__ rw2,
    f16* __restrict__ wsh, float* __restrict__ pri)
{
    int idx = blockIdx.x * 256 + threadIdx.x;
    f16* wt2  = wsh + 0;
    f16* wt3  = wsh + 36864;
    f16* wt4  = wsh + 110592;
    f16* wt5  = wsh + 258048;
    f16* wt6  = wsh + 552960;
    f16* wt7  = wsh + 1142784;
    f16* wt8  = wsh + 1732608;
    f16* wt1  = wsh + 2322432;
    f16* wth1 = wsh + 2324480;
    f16* wth2 = wsh + 2361344;

    auto cw = [](const float* w, f16* wt, int OC, int IC, int i) {
        int oc = i / IC, ic = i - oc * IC;
#pragma unroll
        for (int t = 0; t < 9; ++t)
            wt[((long)t * OC + oc) * IC + ic] = (f16)w[(long)i * 9 + t];
    };
    auto ch = [](const float* lw, const float* cwp, const float* rw, f16* wth, int i) {
        int t = i / 4096;
        int r = (i >> 8) & 15;
        int ic = i & 255;
        float v = 0.f;
        if (r < 2)       v = lw[((long)r * 256 + ic) * 9 + t];
        else if (r < 5)  v = cwp[((long)(r - 2) * 256 + ic) * 9 + t];
        else if (r == 5) v = rw[(long)ic * 9 + t];
        wth[((long)t * 16 + r) * 256 + ic] = (f16)v;
    };

    if (idx < 4096)        cw(w2, wt2, 64, 64, idx);
    else if (idx < 12288)  cw(w3, wt3, 128, 64, idx - 4096);
    else if (idx < 28672)  cw(w4, wt4, 128, 128, idx - 12288);
    else if (idx < 61440)  cw(w5, wt5, 256, 128, idx - 28672);
    else if (idx < 126976) cw(w6, wt6, 256, 256, idx - 61440);
    else if (idx < 192512) cw(w7, wt7, 256, 256, idx - 126976);
    else if (idx < 258048) cw(w8, wt8, 256, 256, idx - 192512);
    else if (idx < 258112) {
        int oc = idx - 258048;
#pragma unroll
        for (int k = 0; k < 32; ++k) {
            f16 v = (f16)0.f;
            if (k < 18) {
                int t = k >> 1, ic = k & 1;
                v = (f16)w1[((long)oc * 2 + ic) * 9 + t];
            }
            wt1[oc * 32 + k] = v;
        }
    }
    else if (idx < 294976) ch(lw1, cw1, rw1, wth1, idx - 258112);
    else if (idx < 331840) ch(lw2, cw2, rw2, wth2, idx - 294976);
    else if (idx < 336960) {
        int r = idx - 331840;
        float cx, cy;
        if (r < 4096) {
            int i = r >> 6, j = r & 63;
            cx = (j + 0.5f) / 64.0f; cy = (i + 0.5f) / 64.0f;
        } else {
            int rr = r - 4096;
            int i = rr >> 5, j = rr & 31;
            cx = (j + 0.5f) / 32.0f; cy = (i + 0.5f) / 32.0f;
        }
        pri[2 * r]     = cx;
        pri[2 * r + 1] = cy;
    }
}

// ---------------- l2norm + fused output-halo zero (f16x8 vectorized) ----------------
__global__ __launch_bounds__(256) void l2nh_k(const f16* __restrict__ in, const float* __restrict__ g,
                                              f16* __restrict__ out, int W, long stride,
                                              int total, int items)
{
    int i = blockIdx.x * 256 + threadIdx.x;
    const int Wp = W + 2;
    if (i < total) {
        int b = i / (W * W);
        int rem = i - b * W * W;
        int y = rem / W, x = rem - y * W;
        long off = (long)b * stride + ((long)(y + 1) * Wp + x + 1) * 256;
        const f16* p = in + off;
        f16* q = out + off;
        float s = 0.f;
        for (int gg = 0; gg < 32; ++gg) {
            f16x8 v = *(const f16x8*)(p + gg * 8);
#pragma unroll
            for (int j = 0; j < 8; ++j) { float f = (float)v[j]; s = fmaf(f, f, s); }
        }
        float inv = 1.f / (sqrtf(s) + 1e-10f);
        for (int gg = 0; gg < 32; ++gg) {
            f16x8 v = *(const f16x8*)(p + gg * 8);
            f16x8 o;
#pragma unroll
            for (int j = 0; j < 8; ++j) o[j] = (f16)(g[gg * 8 + j] * ((float)v[j] * inv));
            *(f16x8*)(q + gg * 8) = o;
        }
        return;
    }
    int j = i - total;
    const int perPos = 2 * Wp + 2 * W;
    const int per = perPos * 32;
    if (j >= items * per) return;
    int n = j / per;
    int k = j - n * per;
    int p = k >> 5;
    int gg = k & 31;
    int row, col;
    if (p < Wp)            { row = 0;     col = p; }
    else if (p < 2 * Wp)   { row = W + 1; col = p - Wp; }
    else { int q = p - 2 * Wp; row = 1 + (q >> 1); col = (q & 1) ? (W + 1) : 0; }
    f16x8 z8;
#pragma unroll
    for (int jj = 0; jj < 8; ++jj) z8[jj] = (f16)0.f;
    *(f16x8*)&out[(long)n * stride + ((long)row * Wp + col) * 256 + gg * 8] = z8;
}

// ---------------- maxpool x6p->p4 + fused p4-halo zero ----------------
__global__ __launch_bounds__(256) void mph_k(const f16* __restrict__ in, f16* __restrict__ out)
{
    const int TOT = 8 * 32 * 32 * 32;
    int idx = blockIdx.x * 256 + threadIdx.x;
    if (idx < TOT) {
        int gg = idx & 31;
        int xo = (idx >> 5) & 31;
        int yo = (idx >> 10) & 31;
        int b = idx >> 15;
        const f16* p = in + (long)b * 1115136 + ((long)(2 * yo + 1) * 66 + 2 * xo + 1) * 256 + gg * 8;
        f16x8 a0 = *(const f16x8*)p;
        f16x8 a1 = *(const f16x8*)(p + 256);
        f16x8 a2 = *(const f16x8*)(p + 66 * 256);
        f16x8 a3 = *(const f16x8*)(p + 66 * 256 + 256);
        f16x8 o;
#pragma unroll
        for (int j = 0; j < 8; ++j)
            o[j] = (f16)fmaxf(fmaxf((float)a0[j], (float)a1[j]), fmaxf((float)a2[j], (float)a3[j]));
        *(f16x8*)(out + (long)b * 295936 + ((long)(yo + 1) * 34 + xo + 1) * 256 + gg * 8) = o;
        return;
    }
    int j = idx - TOT;
    const int per = (2 * 34 + 2 * 32) * 32;
    if (j >= 8 * per) return;
    int n = j / per;
    int k = j - n * per;
    int p = k >> 5;
    int gg = k & 31;
    int row, col;
    if (p < 34)       { row = 0;  col = p; }
    else if (p < 68)  { row = 33; col = p - 34; }
    else { int q = p - 68; row = 1 + (q >> 1); col = (q & 1) ? 33 : 0; }
    f16x8 z8;
#pragma unroll
    for (int jj = 0; jj < 8; ++jj) z8[jj] = (f16)0.f;
    *(f16x8*)&out[(long)n * 295936 + ((long)row * 34 + col) * 256 + gg * 8] = z8;
}

// ---------------- launch ----------------
extern "C" void kernel_launch(void* const* d_in, const int* in_sizes, int n_in,
                              void* d_out, int out_size, void* d_ws, size_t ws_size,
                              hipStream_t stream)
{
    const float* x  = (const float*)d_in[0];
    const float* w1 = (const float*)d_in[1];  const float* b1 = (const float*)d_in[2];
    const float* w2 = (const float*)d_in[3];  const float* b2 = (const float*)d_in[4];
    const float* w3 = (const float*)d_in[5];  const float* b3 = (const float*)d_in[6];
    const float* w4 = (const float*)d_in[7];  const float* b4 = (const float*)d_in[8];
    const float* w5 = (const float*)d_in[9];  const float* b5 = (const float*)d_in[10];
    const float* w6 = (const float*)d_in[11]; const float* b6 = (const float*)d_in[12];
    const float* w7 = (const float*)d_in[13]; const float* b7 = (const float*)d_in[14];
    const float* w8 = (const float*)d_in[15]; const float* b8 = (const float*)d_in[16];
    const float* g1 = (const float*)d_in[17]; const float* g2 = (const float*)d_in[18];
    const float* lw1 = (const float*)d_in[19]; const float* lb1 = (const float*)d_in[20];
    const float* lw2 = (const float*)d_in[21]; const float* lb2 = (const float*)d_in[22];
    const float* cw1 = (const float*)d_in[23]; const float* cb1 = (const float*)d_in[24];
    const float* cw2 = (const float*)d_in[25]; const float* cb2 = (const float*)d_in[26];
    const float* rw1 = (const float*)d_in[27]; const float* rb1 = (const float*)d_in[28];
    const float* rw2 = (const float*)d_in[29]; const float* rb2 = (const float*)d_in[30];

    f16* wsh = (f16*)d_ws;
    f16* wt2  = wsh + 0;
    f16* wt3  = wsh + 36864;
    f16* wt4  = wsh + 110592;
    f16* wt5  = wsh + 258048;
    f16* wt6  = wsh + 552960;
    f16* wt7  = wsh + 1142784;
    f16* wt8  = wsh + 1732608;
    f16* wt1  = wsh + 2322432;
    f16* wth1 = wsh + 2324480;
    f16* wth2 = wsh + 2361344;
    f16* x6p  = wsh + 2398208;   // 8*66*66*256 = 8921088
    const long PI = 11319296;    // group region base

    const long A1S = 16908544;   // 514*514*64
    const long P1S = 4260096;    // 258*258*64
    const long A3S = 8520192;    // 258*258*128 (aliases a1 region)
    const long P2S = 2163200;    // 130*130*128 (aliases p1 region)
    const long A5S = 4326400;    // 130*130*256 (aliases a1 region)
    const long PH2 = 18391040;   // phase-2 footprint (s1..s2)

    int G = 1;
    for (int g = 8; g >= 1; g >>= 1) {
        long ext = (long)g * (A1S + P1S); if (ext < PH2) ext = PH2;
        if (2.0 * (double)(PI + ext) <= (double)ws_size) { G = g; break; }
    }
    const int NGRP = 8 / G;

    f16* a1 = wsh + PI;                    // G x A1S (aliased: a3, a5)
    f16* p1 = wsh + PI + (long)G * A1S;    // G x P1S (aliased: p2)
    f16* a3 = a1;
    f16* p2 = p1;
    f16* a5 = a1;
    // phase-2 (after group loop, group region dead)
    f16* s1 = wsh + PI;
    f16* p4 = wsh + PI + 8921088;
    f16* a7 = wsh + PI + 11288576;
    f16* a8 = wsh + PI + 13656064;
    f16* s2 = wsh + PI + 16023552;

    float* loc  = (float*)d_out;
    float* conf = loc + 81920;
    float* regr = loc + 204800;
    float* pri  = loc + 245760;

    // weights + head-weights + priors in one dispatch
    cvt_all_k<<<dim3((336960 + 255) / 256), 256, 0, stream>>>(
        w1, w2, w3, w4, w5, w6, w7, w8, lw1, cw1, rw1, lw2, cw2, rw2, wsh, pri);

    // conv1..conv6, G items per dispatch; every conv self-zeroes its output halo
    for (int grp = 0; grp < NGRP; ++grp) {
        f16* x6g = x6p + (long)grp * G * 1115136;
        convmf1_k<<<dim3(8, 64, G), 256, 0, stream>>>(x, grp * G, wt1, b1, a1, A1S);
        convmf_k<64, 64, 64, 2, 2, 8, 2, true><<<dim3(8, 128, G), 256, 0, stream>>>(
            a1, wt2, b2, p1, 512, 512, 1, A1S, P1S);
        convmf_k<64, 128, 64, 2, 2, 8, 2, false><<<dim3(4, 64, 2 * G), 256, 0, stream>>>(
            p1, wt3, b3, a3, 256, 256, 2, P1S, A3S);
        convmf_k<128, 128, 64, 2, 2, 8, 2, true><<<dim3(4, 64, 2 * G), 256, 0, stream>>>(
            a3, wt4, b4, p2, 256, 256, 2, A3S, P2S);
        convmf_k<128, 256, 64, 2, 2, 8, 2, false><<<dim3(2, 32, 4 * G), 256, 0, stream>>>(
            p2, wt5, b5, a5, 128, 128, 4, P2S, A5S);
        convmf_k<256, 256, 64, 2, 2, 8, 2, true><<<dim3(2, 32, 4 * G), 256, 0, stream>>>(
            a5, wt6, b6, x6g, 128, 128, 4, A5S, 1115136);
    }

    // s1 = l2norm(x6p) + s1-halo zero (one dispatch)
    {
        const int total = 8 * 4096;
        const int halo = 8 * (2 * 66 + 2 * 64) * 32;
        l2nh_k<<<dim3((total + halo + 255) / 256), 256, 0, stream>>>(
            x6p, g1, s1, 64, 1115136, total, 8);
    }
    // p4 = maxpool(x6p) + p4-halo zero (one dispatch)
    mph_k<<<dim3((262144 + 8 * 4224 + 255) / 256), 256, 0, stream>>>(x6p, p4);

    // conv7/8 self-zero a7/a8 halos in their epilogues
    convmf_k<256, 256, 32, 2, 2, 4, 2, false><<<dim3(1, 8, 32), 256, 0, stream>>>(
        p4, wt7, b7, a7, 32, 32, 4, 295936, 295936);
    convmf_k<256, 256, 32, 2, 2, 4, 2, false><<<dim3(1, 8, 32), 256, 0, stream>>>(
        a7, wt8, b8, a8, 32, 32, 4, 295936, 295936);

    // s2 = l2norm(a8) + s2-halo zero (one dispatch)
    {
        const int total = 8 * 1024;
        const int halo = 8 * (2 * 34 + 2 * 32) * 32;
        l2nh_k<<<dim3((total + halo + 255) / 256), 256, 0, stream>>>(
            a8, g2, s2, 32, 295936, total, 8);
    }

    // both head scales in one dispatch
    headall_k<<<dim3(1, 80, 8), 256, 0, stream>>>(
        s1, s2, wth1, wth2, lb1, cb1, rb1, lb2, cb2, rb2, loc, conf, regr);

    (void)in_sizes; (void)n_in; (void)out_size; (void)ws_size;
}